// Round 2
// baseline (704.753 us; speedup 1.0000x reference)
//
#include <hip/hip_runtime.h>

#define N_NODES 10000
#define F_IN    256
#define H1      128
#define H2      64
#define NEDGE   320000
#define M_TOT   (NEDGE + N_NODES)

// ---------------------------------------------------------------- graph prep
// NOTE: harness passes integer inputs as int32 (edge_index int64 -> int32).

__global__ void k_init(float* deg, int* cnt) {
    int i = blockIdx.x * blockDim.x + threadIdx.x;
    if (i < N_NODES) { deg[i] = 1.0f; cnt[i] = 1; }   // self-loop weight 1, count 1
}

__global__ void k_count(const int* __restrict__ ei, const float* __restrict__ w,
                        float* deg, int* cnt) {
    int e = blockIdx.x * blockDim.x + threadIdx.x;
    if (e < NEDGE) {
        int c = ei[NEDGE + e];                // col
        atomicAdd(&deg[c], w[e]);
        atomicAdd(&cnt[c], 1);
    }
}

__global__ void k_rsqrt(float* deg) {
    int i = blockIdx.x * blockDim.x + threadIdx.x;
    if (i < N_NODES) deg[i] = rsqrtf(deg[i]);         // deg >= 1 always (self loop)
}

// exclusive scan of cnt[0..N) -> ptr, one block of 1024 threads, 10 items each
__global__ void k_scan(const int* __restrict__ cnt, int* __restrict__ ptr,
                       int* __restrict__ cur) {
    __shared__ int part[1024];
    int t = threadIdx.x;
    int base = t * 10;
    int local[10];
    int s = 0;
#pragma unroll
    for (int j = 0; j < 10; j++) {
        int idx = base + j;
        int v = (idx < N_NODES) ? cnt[idx] : 0;
        local[j] = s;
        s += v;
    }
    part[t] = s;
    __syncthreads();
    for (int off = 1; off < 1024; off <<= 1) {
        int v = (t >= off) ? part[t - off] : 0;
        __syncthreads();
        part[t] += v;
        __syncthreads();
    }
    int excl = t ? part[t - 1] : 0;
#pragma unroll
    for (int j = 0; j < 10; j++) {
        int idx = base + j;
        if (idx < N_NODES) {
            int p = excl + local[j];
            ptr[idx] = p;
            cur[idx] = p;
        }
    }
    if (t == 1023) ptr[N_NODES] = part[1023];
}

// scatter edges (+self loops) into CSR-by-col with precomputed norm
__global__ void k_scatter(const int* __restrict__ ei, const float* __restrict__ w,
                          const float* __restrict__ dis, int* cur,
                          int* __restrict__ src, float* __restrict__ wgt) {
    int t = blockIdx.x * blockDim.x + threadIdx.x;
    if (t >= M_TOT) return;
    int r, c; float nw;
    if (t < NEDGE) {
        r = ei[t];
        c = ei[NEDGE + t];
        nw = dis[r] * w[t] * dis[c];
    } else {
        r = c = t - NEDGE;
        float d = dis[r];
        nw = d * d;
    }
    int pos = atomicAdd(&cur[c], 1);
    src[pos] = r;
    wgt[pos] = nw;
}

// ---------------------------------------------------------------- dense GEMMs

// hw = x @ W1   [10000,256]x[256,128]; 8 rows/block, 128 threads (1 col each)
__global__ __launch_bounds__(128) void k_gemm1(const float* __restrict__ x,
                                               const float* __restrict__ W1,
                                               float* __restrict__ hw) {
    __shared__ float xs[8 * F_IN];
    int i0 = blockIdx.x * 8;
    int t = threadIdx.x;
    const float4* xsrc = (const float4*)(x + (size_t)i0 * F_IN);
    float4* xd = (float4*)xs;
#pragma unroll
    for (int j = 0; j < 4; j++) xd[t + j * 128] = xsrc[t + j * 128];
    __syncthreads();
    float acc[8] = {0, 0, 0, 0, 0, 0, 0, 0};
    for (int k = 0; k < F_IN; k++) {
        float wv = W1[k * H1 + t];
#pragma unroll
        for (int r = 0; r < 8; r++) acc[r] += xs[r * F_IN + k] * wv;  // same-addr LDS broadcast
    }
#pragma unroll
    for (int r = 0; r < 8; r++) hw[(size_t)(i0 + r) * H1 + t] = acc[r];
}

// t2 = h1 @ W2, t3 = h1 @ W3  [10000,128]x[128,64] twice; wave0->W2, wave1->W3
__global__ __launch_bounds__(128) void k_gemm23(const float* __restrict__ h1,
                                                const float* __restrict__ W2,
                                                const float* __restrict__ W3,
                                                float* __restrict__ t2,
                                                float* __restrict__ t3) {
    __shared__ float hs[8 * H1];
    int i0 = blockIdx.x * 8;
    int t = threadIdx.x;
    const float4* hsrc = (const float4*)(h1 + (size_t)i0 * H1);
    float4* hd = (float4*)hs;
#pragma unroll
    for (int j = 0; j < 2; j++) hd[t + j * 128] = hsrc[t + j * 128];
    __syncthreads();
    int f = t & 63;
    int sel = t >> 6;                      // wave-uniform
    const float* W = sel ? W3 : W2;
    float acc[8] = {0, 0, 0, 0, 0, 0, 0, 0};
    for (int k = 0; k < H1; k++) {
        float wv = W[k * H2 + f];
#pragma unroll
        for (int r = 0; r < 8; r++) acc[r] += hs[r * H1 + k] * wv;
    }
    float* o = sel ? t3 : t2;
#pragma unroll
    for (int r = 0; r < 8; r++) o[(size_t)(i0 + r) * H2 + f] = acc[r];
}

// ---------------------------------------------------------------- aggregations

// h1 = relu(segsum(norm * hw[row]) + b1)   one block per node, 128 feats
__global__ __launch_bounds__(128) void k_agg1(const int* __restrict__ ptr,
                                              const int* __restrict__ src,
                                              const float* __restrict__ wgt,
                                              const float* __restrict__ hw,
                                              const float* __restrict__ b1,
                                              float* __restrict__ h1) {
    int i = blockIdx.x;
    int f = threadIdx.x;
    int jb = ptr[i], je = ptr[i + 1];
    float acc = b1[f];
    for (int j = jb; j < je; j++)
        acc += wgt[j] * hw[(size_t)src[j] * H1 + f];
    h1[(size_t)i * H1 + f] = fmaxf(acc, 0.0f);
}

// mu = segsum(norm * t2[row]) + b2 ; logvar = ... t3/b3.  wave0->mu, wave1->logvar
__global__ __launch_bounds__(128) void k_agg2(const int* __restrict__ ptr,
                                              const int* __restrict__ src,
                                              const float* __restrict__ wgt,
                                              const float* __restrict__ t2,
                                              const float* __restrict__ t3,
                                              const float* __restrict__ b2,
                                              const float* __restrict__ b3,
                                              float* __restrict__ mu,
                                              float* __restrict__ lv) {
    int i = blockIdx.x;
    int t = threadIdx.x;
    int f = t & 63;
    int sel = t >> 6;                      // wave-uniform
    const float* tin = sel ? t3 : t2;
    float acc = sel ? b3[f] : b2[f];
    int jb = ptr[i], je = ptr[i + 1];
    for (int j = jb; j < je; j++)
        acc += wgt[j] * tin[(size_t)src[j] * H2 + f];
    float* o = sel ? lv : mu;
    o[(size_t)i * H2 + f] = acc;
}

// ---------------------------------------------------------------- adj = z z^T

// 128x128 tile per block (256 thr), K=64 one shot, 8x8 micro-tile/thread.
// LDS K-major: As[k][m], Bs[k][n] -> ds_read_b128 along m/n. 64KB LDS, 2 blk/CU.
__global__ __launch_bounds__(256) void k_adj(const float* __restrict__ z,
                                             float* __restrict__ adj) {
    __shared__ float As[64][128];
    __shared__ float Bs[64][128];
    int tid = threadIdx.x;
    int tx = tid & 15, ty = tid >> 4;
    int rowBase = blockIdx.y * 128, colBase = blockIdx.x * 128;

    // stage tiles transposed: 2 threads/row, 32 cols each; writes are 2-way (free)
    int m = tid >> 1;
    int kh = (tid & 1) * 32;
    {
        int gr = rowBase + m;
        const float4* zr = (const float4*)(z + (size_t)gr * H2 + kh);
#pragma unroll
        for (int q = 0; q < 8; q++) {
            float4 v = make_float4(0.f, 0.f, 0.f, 0.f);
            if (gr < N_NODES) v = zr[q];
            int k = kh + q * 4;
            As[k][m] = v.x; As[k + 1][m] = v.y; As[k + 2][m] = v.z; As[k + 3][m] = v.w;
        }
        int gc = colBase + m;
        const float4* zc = (const float4*)(z + (size_t)gc * H2 + kh);
#pragma unroll
        for (int q = 0; q < 8; q++) {
            float4 v = make_float4(0.f, 0.f, 0.f, 0.f);
            if (gc < N_NODES) v = zc[q];
            int k = kh + q * 4;
            Bs[k][m] = v.x; Bs[k + 1][m] = v.y; Bs[k + 2][m] = v.z; Bs[k + 3][m] = v.w;
        }
    }
    __syncthreads();

    float acc[8][8];
#pragma unroll
    for (int i = 0; i < 8; i++)
#pragma unroll
        for (int j = 0; j < 8; j++) acc[i][j] = 0.f;

    for (int k = 0; k < 64; k++) {
        float4 a0 = *(const float4*)&As[k][ty * 4];
        float4 a1 = *(const float4*)&As[k][ty * 4 + 64];
        float4 b0 = *(const float4*)&Bs[k][tx * 4];
        float4 b1v = *(const float4*)&Bs[k][tx * 4 + 64];
        float a[8] = {a0.x, a0.y, a0.z, a0.w, a1.x, a1.y, a1.z, a1.w};
        float b[8] = {b0.x, b0.y, b0.z, b0.w, b1v.x, b1v.y, b1v.z, b1v.w};
#pragma unroll
        for (int i = 0; i < 8; i++)
#pragma unroll
            for (int j = 0; j < 8; j++) acc[i][j] += a[i] * b[j];
    }

#pragma unroll
    for (int i = 0; i < 8; i++) {
        int rm = rowBase + ty * 4 + ((i < 4) ? i : 64 + (i - 4));
        if (rm >= N_NODES) continue;
        float* orow = adj + (size_t)rm * N_NODES;
        int c0 = colBase + tx * 4;
        if (c0 < N_NODES)
            *(float4*)&orow[c0] = make_float4(acc[i][0], acc[i][1], acc[i][2], acc[i][3]);
        int c1 = c0 + 64;
        if (c1 < N_NODES)
            *(float4*)&orow[c1] = make_float4(acc[i][4], acc[i][5], acc[i][6], acc[i][7]);
    }
}

// ---------------------------------------------------------------- launch

extern "C" void kernel_launch(void* const* d_in, const int* in_sizes, int n_in,
                              void* d_out, int out_size, void* d_ws, size_t ws_size,
                              hipStream_t stream) {
    const float* x  = (const float*)d_in[0];
    const int*   ei = (const int*)d_in[1];      // harness passes ints as int32
    const float* w  = (const float*)d_in[2];
    const float* W1 = (const float*)d_in[3];
    const float* b1 = (const float*)d_in[4];
    const float* W2 = (const float*)d_in[5];
    const float* b2 = (const float*)d_in[6];
    const float* W3 = (const float*)d_in[7];
    const float* b3 = (const float*)d_in[8];

    float* out = (float*)d_out;
    float* adj = out;
    float* mu  = out + (size_t)N_NODES * N_NODES;
    float* lv  = mu + (size_t)N_NODES * H2;

    // Scratch lives in the tail of the adj region of d_out (offset 320 MB of
    // the 400 MB adj block). It is fully dead before k_adj overwrites it, and
    // every scratch array is written before it is read on every call. This
    // avoids any assumption about ws_size.  total scratch ~18.2 MB.
    float* ws  = out + 80000000;
    float* deg = ws;                       // 10240 floats (becomes dis in-place)
    int*   cnt = (int*)(ws + 10240);       // 10240
    int*   ptr = (int*)(ws + 20480);       // 10240 (10001 used)
    int*   cur = (int*)(ws + 30720);       // 10240
    int*   src = (int*)(ws + 40960);       // 330240
    float* wgt = ws + 371200;              // 330240
    float* hw  = ws + 701440;              // 1,280,000
    float* h1  = ws + 1981440;             // 1,280,000
    float* t2  = ws + 3261440;             // 640,000
    float* t3  = ws + 3901440;             // 640,000  (ends at ws+4,541,440)

    hipLaunchKernelGGL(k_init,    dim3((N_NODES + 255) / 256), dim3(256), 0, stream, deg, cnt);
    hipLaunchKernelGGL(k_count,   dim3((NEDGE + 255) / 256),   dim3(256), 0, stream, ei, w, deg, cnt);
    hipLaunchKernelGGL(k_rsqrt,   dim3((N_NODES + 255) / 256), dim3(256), 0, stream, deg);
    hipLaunchKernelGGL(k_scan,    dim3(1), dim3(1024), 0, stream, cnt, ptr, cur);
    hipLaunchKernelGGL(k_scatter, dim3((M_TOT + 255) / 256),   dim3(256), 0, stream, ei, w, deg, cur, src, wgt);
    hipLaunchKernelGGL(k_gemm1,   dim3(N_NODES / 8),  dim3(128), 0, stream, x, W1, hw);
    hipLaunchKernelGGL(k_agg1,    dim3(N_NODES),      dim3(128), 0, stream, ptr, src, wgt, hw, b1, h1);
    hipLaunchKernelGGL(k_gemm23,  dim3(N_NODES / 8),  dim3(128), 0, stream, h1, W2, W3, t2, t3);
    hipLaunchKernelGGL(k_agg2,    dim3(N_NODES),      dim3(128), 0, stream, ptr, src, wgt, t2, t3, b2, b3, mu, lv);

    dim3 g((N_NODES + 127) / 128, (N_NODES + 127) / 128);
    hipLaunchKernelGGL(k_adj, g, dim3(256), 0, stream, mu, adj);
}